// Round 3
// baseline (249.795 us; speedup 1.0000x reference)
//
#include <hip/hip_runtime.h>
#include <math.h>
#include <stdint.h>

#define NF_     13776
#define R_      128
#define NPIX_   (R_ * R_)
#define CH_     256
#define NSLICE_ 32
#define FPS_    ((NF_ + NSLICE_ - 1) / NSLICE_)
#define NBKT_   256

typedef unsigned long long u64;
typedef unsigned int u32;

// exact f32 constants matching the JAX reference
#define EYEZ_F     (-2.7320508075688772935f)     // -(1/tan(30deg) + 1)
#define INV_FAR_F  (0.04f)
#define INV_NEAR_F (10.0f)
#define FAR_BITS   0x41C80000u                   // bits of 25.0f
#define HIT_THR_F  ((float)(25.0 * (1.0 - 1e-06)))
#define SENTINEL_  (((u64)FAR_BITS << 32))       // depth=FAR, fid=0
// z-bucket mapping: bucket = min(255, (int)(zeff*32)), lower bound with margin
#define BKT_SCALE  32.0f
#define BKT_LO(b)  ((float)(b) * (0.03125f * 0.999999f))

static __device__ __forceinline__ float pix_coord(int j) {
    // (2*j + 1 - 128)/128 : exact in f32
    return (2.0f * (float)j + 1.0f - 128.0f) / 128.0f;
}

// ---------------- per-face preprocess ----------------
__global__ __launch_bounds__(256) void kpre(const float* __restrict__ verts,
                                            const int* __restrict__ faces,
                                            float4* __restrict__ fq0,
                                            float4* __restrict__ fq1,
                                            float4* __restrict__ fq2,
                                            float4* __restrict__ bbx,
                                            int* __restrict__ cull)
{
#pragma clang fp contract(off)
    int f = blockIdx.x * 256 + threadIdx.x;
    if (f >= NF_) return;
    int i0 = faces[3*f+0], i1 = faces[3*f+1], i2 = faces[3*f+2];
    float x0 = verts[3*i0+0], y0 = verts[3*i0+1], z0 = verts[3*i0+2] - EYEZ_F;
    float x1 = verts[3*i1+0], y1 = verts[3*i1+1], z1 = verts[3*i1+2] - EYEZ_F;
    float x2 = verts[3*i2+0], y2 = verts[3*i2+1], z2 = verts[3*i2+2] - EYEZ_F;

    float a = y1 - y2;
    float b = x2 - x1;
    float c = y2 - y0;
    float d = x0 - x2;
    float e = y0 - y2;
    float det = a * d + b * e;                   // no FMA (contract off)
    bool det_ok = fabsf(det) > 1e-10f;
    float dets = det_ok ? det : 1e-10f;
    bool zpos = (z0 > 0.1f) && (z1 > 0.1f) && (z2 > 0.1f);

    // conservative prune bound: any valid candidate's computed depth > zmin_eff
    float zmin_eff = fminf(z0, fminf(z1, z2)) * 0.99999f;

    fq0[f] = make_float4(a, b, c, d);
    fq1[f] = make_float4(x2, y2, dets, zmin_eff);
    fq2[f] = make_float4(z0, z1, z2, __uint_as_float((u32)f));
    bbx[f] = make_float4(fminf(x0, fminf(x1, x2)) - 1e-4f,
                         fmaxf(x0, fmaxf(x1, x2)) + 1e-4f,
                         fminf(y0, fminf(y1, y2)) - 1e-4f,
                         fmaxf(y0, fmaxf(y1, y2)) + 1e-4f);
    cull[f] = (det_ok && zpos) ? 0 : 1;
}

static __device__ __forceinline__ void tile_masks(float4 bb, int& xm, int& ym) {
    xm = 0; ym = 0;
    #pragma unroll
    for (int t = 0; t < 8; ++t) {
        float tx0 = pix_coord(t * 16), tx1 = pix_coord(t * 16 + 15);
        if (bb.x <= tx1 && bb.y >= tx0) xm |= 1 << t;
        float ty1 = -pix_coord(t * 16), ty0 = -pix_coord(t * 16 + 15);
        if (bb.z <= ty1 && bb.w >= ty0) ym |= 1 << t;
    }
}

// ---------------- count per (tile, z-bucket) ----------------
__global__ __launch_bounds__(256) void kcount(const float4* __restrict__ bbx,
                                              const float4* __restrict__ fq1,
                                              const int* __restrict__ cull,
                                              u32* __restrict__ count)
{
#pragma clang fp contract(off)
    int f = blockIdx.x * 256 + threadIdx.x;
    if (f >= NF_ || cull[f]) return;
    int xm, ym; tile_masks(bbx[f], xm, ym);
    int bkt = min(255, (int)(fq1[f].w * BKT_SCALE));
    for (int tr = 0; tr < 8; ++tr) if (ym & (1 << tr))
        for (int tc = 0; tc < 8; ++tc) if (xm & (1 << tc))
            atomicAdd(&count[(tr * 8 + tc) * NBKT_ + bkt], 1u);
}

// ---------------- per-tile exclusive prefix over buckets ----------------
__global__ __launch_bounds__(256) void kprefix(const u32* __restrict__ count,
                                               u32* __restrict__ offs2,
                                               int* __restrict__ len)
{
    __shared__ u32 s[NBKT_];
    int t = blockIdx.x, b = threadIdx.x;
    u32 v = count[t * NBKT_ + b];
    s[b] = v;
    __syncthreads();
    for (int d = 1; d < NBKT_; d <<= 1) {
        u32 add = (b >= d) ? s[b - d] : 0;
        __syncthreads();
        s[b] += add;
        __syncthreads();
    }
    offs2[t * NBKT_ + b] = s[b] - v;     // exclusive
    if (b == NBKT_ - 1) len[t] = (int)s[NBKT_ - 1];
}

// ---------------- scatter faces into bucket-sorted per-tile lists ----------------
__global__ __launch_bounds__(256) void kscatter(const float4* __restrict__ bbx,
                                                const float4* __restrict__ fq1,
                                                const int* __restrict__ cull,
                                                u32* __restrict__ offs2,
                                                u32* __restrict__ list)
{
#pragma clang fp contract(off)
    int f = blockIdx.x * 256 + threadIdx.x;
    if (f >= NF_ || cull[f]) return;
    int xm, ym; tile_masks(bbx[f], xm, ym);
    int bkt = min(255, (int)(fq1[f].w * BKT_SCALE));
    u32 entry = ((u32)bkt << 16) | (u32)f;       // fid < 16384 fits
    for (int tr = 0; tr < 8; ++tr) if (ym & (1 << tr))
        for (int tc = 0; tc < 8; ++tc) if (xm & (1 << tc)) {
            int t = tr * 8 + tc;
            u32 slot = atomicAdd(&offs2[t * NBKT_ + bkt], 1u);
            list[(size_t)t * NF_ + slot] = entry;
        }
}

// ---------------- depth-sorted scan: block = 8x8 px quadrant of a tile ----------------
__global__ __launch_bounds__(64) void kscan3(const float4* __restrict__ fq0,
                                             const float4* __restrict__ fq1,
                                             const float4* __restrict__ fq2,
                                             const int* __restrict__ len,
                                             const u32* __restrict__ list,
                                             u64* __restrict__ pd64)
{
#pragma clang fp contract(off)
    __shared__ float4 c0[CH_], c1[CH_], c2[CH_];
    const int t = blockIdx.x >> 2, q = blockIdx.x & 3;
    const int tid = threadIdx.x;
    const int len_t = len[t];
    const int ii = (t >> 3) * 16 + (q >> 1) * 8 + (tid >> 3);
    const int jj = (t & 7) * 16 + (q & 1) * 8 + (tid & 7);
    const int p = ii * R_ + jj;
    const float px = pix_coord(jj);
    const float py = -pix_coord(ii);
    const u32* lp = list + (size_t)t * NF_;

    u64 best = SENTINEL_ | 0xFFFFFFFFull;        // (FAR, miss marker)
    float bestd = 25.0f;

    for (int base = 0; base < len_t; base += CH_) {
        // bucket lower bound of all remaining entries (list ascending by bucket)
        u32 e0 = lp[base];
        float blo = BKT_LO(e0 >> 16);
        if (__all(blo > bestd)) break;           // no remaining candidate can win anywhere

        const int K = min(CH_, len_t - base);
        for (int k = tid; k < K; k += 64) {
            u32 e = lp[base + k];
            int f = (int)(e & 0xFFFFu);
            c0[k] = fq0[f];
            c1[k] = fq1[f];
            c2[k] = fq2[f];
        }
        __syncthreads();

        for (int k = 0; k < K; ++k) {
            float4 q1 = c1[k];                   // x2,y2,det,zmin_eff
            if (q1.w > bestd) continue;          // strictly worse: cannot win or tie
            float4 q0 = c0[k];                   // a,b,c,d
            float dx = px - q1.x, dy = py - q1.y;
            float n0 = q0.x * dx + q0.y * dy;
            float n1 = q0.z * dx + q0.w * dy;
            u32 sd = __float_as_uint(q1.z) >> 31;
            bool s0 = (n0 == 0.0f) || ((__float_as_uint(n0) >> 31) == sd);
            bool s1 = (n1 == 0.0f) || ((__float_as_uint(n1) >> 31) == sd);
            if (!(s0 && s1)) continue;
            float w0 = n0 / q1.z;
            float w1 = n1 / q1.z;
            float w2 = 1.0f - w0 - w1;
            if (!(w2 >= 0.0f)) continue;
            float4 q2 = c2[k];                   // z0,z1,z2,fid
            float invz = w0 / q2.x + w1 / q2.y + w2 / q2.z;
            if (invz > INV_FAR_F) {
                float clz = fminf(fmaxf(invz, INV_FAR_F), INV_NEAR_F);
                float dep = 1.0f / clz;
                u64 cand = ((u64)__float_as_uint(dep) << 32) | (u64)__float_as_uint(q2.w);
                if (cand < best) { best = cand; bestd = __uint_as_float((u32)(best >> 32)); }
            }
        }
        __syncthreads();
    }
    pd64[p] = ((u32)best == 0xFFFFFFFFu) ? SENTINEL_ : best;   // sole writer: plain store
}

// ---------------- fallback slice scan (ws too small; unused normally) ----------------
__global__ __launch_bounds__(256) void kinit(u64* __restrict__ pd64)
{
    int p = blockIdx.x * 256 + threadIdx.x;
    if (p < NPIX_) pd64[p] = SENTINEL_;
}

__global__ __launch_bounds__(256) void kscanS(const float4* __restrict__ fq0,
                                              const float4* __restrict__ fq1,
                                              const float4* __restrict__ fq2,
                                              const float4* __restrict__ bbx,
                                              const int* __restrict__ cull,
                                              u64* __restrict__ pd64)
{
#pragma clang fp contract(off)
    const int t = blockIdx.x, s = blockIdx.y;
    const int tid = threadIdx.x;
    const int ii = (t >> 3) * 16 + (tid >> 4);
    const int jj = (t & 7) * 16 + (tid & 15);
    const int p  = ii * R_ + jj;
    const float px = pix_coord(jj);
    const float py = -pix_coord(ii);
    const float tpx0 = pix_coord((t & 7) * 16), tpx1 = pix_coord((t & 7) * 16 + 15);
    const float tpy1 = -pix_coord((t >> 3) * 16), tpy0 = -pix_coord((t >> 3) * 16 + 15);
    const int f0 = s * FPS_, f1 = min(NF_, f0 + FPS_);

    u64 best = SENTINEL_ | 0xFFFFFFFFull;
    float bestd = 25.0f;

    for (int f = f0; f < f1; ++f) {
        if (cull[f]) continue;
        float4 bb = bbx[f];
        if (!(bb.x <= tpx1 && bb.y >= tpx0 && bb.z <= tpy1 && bb.w >= tpy0)) continue;
        float4 q1 = fq1[f];
        if (q1.w > bestd) continue;
        float4 q0 = fq0[f];
        float dx = px - q1.x, dy = py - q1.y;
        float n0 = q0.x * dx + q0.y * dy;
        float n1 = q0.z * dx + q0.w * dy;
        u32 sd = __float_as_uint(q1.z) >> 31;
        bool s0 = (n0 == 0.0f) || ((__float_as_uint(n0) >> 31) == sd);
        bool s1 = (n1 == 0.0f) || ((__float_as_uint(n1) >> 31) == sd);
        if (!(s0 && s1)) continue;
        float w0 = n0 / q1.z;
        float w1 = n1 / q1.z;
        float w2 = 1.0f - w0 - w1;
        if (!(w2 >= 0.0f)) continue;
        float4 q2 = fq2[f];
        float invz = w0 / q2.x + w1 / q2.y + w2 / q2.z;
        if (invz > INV_FAR_F) {
            float clz = fminf(fmaxf(invz, INV_FAR_F), INV_NEAR_F);
            float dep = 1.0f / clz;
            u64 cand = ((u64)__float_as_uint(dep) << 32) | (u64)__float_as_uint(q2.w);
            if (cand < best) { best = cand; bestd = __uint_as_float((u32)(best >> 32)); }
        }
    }
    if ((u32)best != 0xFFFFFFFFu) atomicMin(&pd64[p], best);
}

// ---------------- finalize ----------------
__global__ __launch_bounds__(256) void kfin(const u64* __restrict__ pd64,
                                            const float4* __restrict__ fq0,
                                            const float4* __restrict__ fq1,
                                            const float4* __restrict__ fq2,
                                            const float* __restrict__ tex,
                                            float* __restrict__ out)
{
#pragma clang fp contract(off)
    int p = blockIdx.x * 256 + threadIdx.x;
    if (p >= NPIX_) return;
    int ii = p >> 7, jj = p & 127;

    u64 v = pd64[p];
    float dep = __uint_as_float((u32)(v >> 32));
    int f = (int)(u32)v;

    float r = 0.0f, g = 0.0f, bl = 0.0f, s = 0.0f;
    if (dep < HIT_THR_F) {
        s = 1.0f;
        float4 q0 = fq0[f], q1 = fq1[f], q2 = fq2[f];
        float px = pix_coord(jj);
        float py = -pix_coord(ii);
        float dx = px - q1.x, dy = py - q1.y;
        float w0 = (q0.x * dx + q0.y * dy) / q1.z;
        float w1 = (q0.z * dx + q0.w * dy) / q1.z;
        float w2 = 1.0f - w0 - w1;
        float wt0 = (w0 / q2.x) * dep;
        float wt1 = (w1 / q2.y) * dep;
        float wt2 = (w2 / q2.z) * dep;
        int t0 = (int)fminf(fmaxf(floorf(wt0 * 3.0f), 0.0f), 2.0f);
        int t1 = (int)fminf(fmaxf(floorf(wt1 * 3.0f), 0.0f), 2.0f);
        int t2 = (int)fminf(fmaxf(floorf(wt2 * 3.0f), 0.0f), 2.0f);
        int lin = f * 27 + t0 * 9 + t1 * 3 + t2;
        r  = tex[lin * 3 + 0];
        g  = tex[lin * 3 + 1];
        bl = tex[lin * 3 + 2];
    }
    out[0 * NPIX_ + p] = r;
    out[1 * NPIX_ + p] = g;
    out[2 * NPIX_ + p] = bl;
    out[3 * NPIX_ + p] = s;
}

extern "C" void kernel_launch(void* const* d_in, const int* in_sizes, int n_in,
                              void* d_out, int out_size, void* d_ws, size_t ws_size,
                              hipStream_t stream) {
    const float* verts = (const float*)d_in[0];
    const float* tex   = (const float*)d_in[1];
    const int*   faces = (const int*)d_in[2];
    float* out = (float*)d_out;

    char* ws = (char*)d_ws;
    size_t off = 0;
    u64*    pd64 = (u64*)   (ws + off); off += (size_t)NPIX_ * 8;
    float4* fq0  = (float4*)(ws + off); off += (size_t)NF_ * 16;
    float4* fq1  = (float4*)(ws + off); off += (size_t)NF_ * 16;
    float4* fq2  = (float4*)(ws + off); off += (size_t)NF_ * 16;
    float4* bbx  = (float4*)(ws + off); off += (size_t)NF_ * 16;
    int*    cull = (int*)   (ws + off); off += (size_t)NF_ * 4;
    int*    lenp = (int*)   (ws + off); off += 64 * 4;
    u32*    cnt  = (u32*)   (ws + off); off += (size_t)64 * NBKT_ * 4;
    u32*    off2 = (u32*)   (ws + off); off += (size_t)64 * NBKT_ * 4;
    off = (off + 15) & ~(size_t)15;
    u32*    list = (u32*)   (ws + off);
    size_t need = off + (size_t)64 * NF_ * 4;

    const int FB = (NF_ + 255) / 256;
    kpre<<<FB, 256, 0, stream>>>(verts, faces, fq0, fq1, fq2, bbx, cull);
    if (ws_size >= need) {
        hipMemsetAsync(cnt, 0, (size_t)64 * NBKT_ * 4, stream);
        kcount  <<<FB, 256, 0, stream>>>(bbx, fq1, cull, cnt);
        kprefix <<<64, 256, 0, stream>>>(cnt, off2, lenp);
        kscatter<<<FB, 256, 0, stream>>>(bbx, fq1, cull, off2, list);
        kscan3  <<<256, 64, 0, stream>>>(fq0, fq1, fq2, lenp, list, pd64);
    } else {
        kinit<<<NPIX_ / 256, 256, 0, stream>>>(pd64);
        dim3 g(64, NSLICE_);
        kscanS<<<g, 256, 0, stream>>>(fq0, fq1, fq2, bbx, cull, pd64);
    }
    kfin<<<NPIX_ / 256, 256, 0, stream>>>(pd64, fq0, fq1, fq2, tex, out);
}

// Round 4
// 206.029 us; speedup vs baseline: 1.2124x; 1.2124x over previous
//
#include <hip/hip_runtime.h>
#include <math.h>
#include <stdint.h>

#define NF_     13776
#define R_      128
#define NPIX_   (R_ * R_)
#define CH_     256
#define NCHUNK_ ((NF_ + CH_ - 1) / CH_)          // 54
#define A_CH_   2
#define B_CH_   (NCHUNK_ - A_CH_)                // 52
#define NSLICE_ 32
#define FPS_    ((NF_ + NSLICE_ - 1) / NSLICE_)
#define NBKT_   256

typedef unsigned long long u64;
typedef unsigned int u32;

// exact f32 constants matching the JAX reference
#define EYEZ_F     (-2.7320508075688772935f)     // -(1/tan(30deg) + 1)
#define INV_FAR_F  (0.04f)
#define INV_NEAR_F (10.0f)
#define FAR_BITS   0x41C80000u                   // bits of 25.0f
#define HIT_THR_F  ((float)(25.0 * (1.0 - 1e-06)))
#define SENTINEL_  (((u64)FAR_BITS << 32))       // depth=FAR, fid=0
// z-bucket mapping: bucket = min(255, (int)(zeff*32)); BKT_LO(b) <= zmin_eff of all members
#define BKT_SCALE  32.0f
#define BKT_LO(b)  ((float)(b) * (0.03125f * 0.999999f))

static __device__ __forceinline__ float pix_coord(int j) {
    return (2.0f * (float)j + 1.0f - 128.0f) / 128.0f;   // exact in f32
}

static __device__ __forceinline__ void tile_masks(float4 bb, int& xm, int& ym) {
    xm = 0; ym = 0;
    #pragma unroll
    for (int t = 0; t < 8; ++t) {
        float tx0 = pix_coord(t * 16), tx1 = pix_coord(t * 16 + 15);
        if (bb.x <= tx1 && bb.y >= tx0) xm |= 1 << t;
        float ty1 = -pix_coord(t * 16), ty0 = -pix_coord(t * 16 + 15);
        if (bb.z <= ty1 && bb.w >= ty0) ym |= 1 << t;
    }
}

// ---------------- init: depth buffer sentinel + zero bucket counters ----------------
__global__ __launch_bounds__(256) void kinit(u64* __restrict__ pd64, u32* __restrict__ cnt)
{
    int p = blockIdx.x * 256 + threadIdx.x;
    if (p < NPIX_) pd64[p] = SENTINEL_;
    if (p < 64 * NBKT_) cnt[p] = 0;
}

// ---------------- per-face preprocess + fused (tile, z-bucket) counting ----------------
__global__ __launch_bounds__(256) void kpre(const float* __restrict__ verts,
                                            const int* __restrict__ faces,
                                            float4* __restrict__ fq0,
                                            float4* __restrict__ fq1,
                                            float4* __restrict__ fq2,
                                            float4* __restrict__ bbx,
                                            int* __restrict__ cull,
                                            u32* __restrict__ cnt,
                                            int do_count)
{
#pragma clang fp contract(off)
    int f = blockIdx.x * 256 + threadIdx.x;
    if (f >= NF_) return;
    int i0 = faces[3*f+0], i1 = faces[3*f+1], i2 = faces[3*f+2];
    float x0 = verts[3*i0+0], y0 = verts[3*i0+1], z0 = verts[3*i0+2] - EYEZ_F;
    float x1 = verts[3*i1+0], y1 = verts[3*i1+1], z1 = verts[3*i1+2] - EYEZ_F;
    float x2 = verts[3*i2+0], y2 = verts[3*i2+1], z2 = verts[3*i2+2] - EYEZ_F;

    float a = y1 - y2;
    float b = x2 - x1;
    float c = y2 - y0;
    float d = x0 - x2;
    float e = y0 - y2;
    float det = a * d + b * e;                   // no FMA (contract off)
    bool det_ok = fabsf(det) > 1e-10f;
    float dets = det_ok ? det : 1e-10f;
    bool zpos = (z0 > 0.1f) && (z1 > 0.1f) && (z2 > 0.1f);

    // conservative prune bound: any valid candidate's computed depth > zmin_eff (strict)
    float zmin_eff = fminf(z0, fminf(z1, z2)) * 0.99999f;

    float4 bb = make_float4(fminf(x0, fminf(x1, x2)) - 1e-4f,
                            fmaxf(x0, fmaxf(x1, x2)) + 1e-4f,
                            fminf(y0, fminf(y1, y2)) - 1e-4f,
                            fmaxf(y0, fmaxf(y1, y2)) + 1e-4f);
    int ok = (det_ok && zpos) ? 0 : 1;

    fq0[f] = make_float4(a, b, c, d);
    fq1[f] = make_float4(x2, y2, dets, zmin_eff);
    fq2[f] = make_float4(z0, z1, z2, __uint_as_float((u32)f));
    bbx[f] = bb;
    cull[f] = ok;

    if (do_count && ok == 0) {
        int xm, ym; tile_masks(bb, xm, ym);
        int bkt = min(255, (int)(zmin_eff * BKT_SCALE));
        for (int tr = 0; tr < 8; ++tr) if (ym & (1 << tr))
            for (int tc = 0; tc < 8; ++tc) if (xm & (1 << tc))
                atomicAdd(&cnt[(tr * 8 + tc) * NBKT_ + bkt], 1u);
    }
}

// ---------------- per-tile exclusive prefix over buckets ----------------
__global__ __launch_bounds__(256) void kprefix(const u32* __restrict__ count,
                                               u32* __restrict__ offs2,
                                               int* __restrict__ len)
{
    __shared__ u32 s[NBKT_];
    int t = blockIdx.x, b = threadIdx.x;
    u32 v = count[t * NBKT_ + b];
    s[b] = v;
    __syncthreads();
    for (int d = 1; d < NBKT_; d <<= 1) {
        u32 add = (b >= d) ? s[b - d] : 0;
        __syncthreads();
        s[b] += add;
        __syncthreads();
    }
    offs2[t * NBKT_ + b] = s[b] - v;     // exclusive
    if (b == NBKT_ - 1) len[t] = (int)s[NBKT_ - 1];
}

// ---------------- scatter faces into bucket-sorted per-tile lists ----------------
__global__ __launch_bounds__(256) void kscatter(const float4* __restrict__ bbx,
                                                const float4* __restrict__ fq1,
                                                const int* __restrict__ cull,
                                                u32* __restrict__ offs2,
                                                u32* __restrict__ list)
{
#pragma clang fp contract(off)
    int f = blockIdx.x * 256 + threadIdx.x;
    if (f >= NF_ || cull[f]) return;
    int xm, ym; tile_masks(bbx[f], xm, ym);
    int bkt = min(255, (int)(fq1[f].w * BKT_SCALE));
    u32 entry = ((u32)bkt << 16) | (u32)f;
    for (int tr = 0; tr < 8; ++tr) if (ym & (1 << tr))
        for (int tc = 0; tc < 8; ++tc) if (xm & (1 << tc)) {
            int t = tr * 8 + tc;
            u32 slot = atomicAdd(&offs2[t * NBKT_ + bkt], 1u);
            list[(size_t)t * NF_ + slot] = entry;
        }
}

// ---------------- chunk-parallel scan: block = (tile, chunk); thread = pixel ----------------
__global__ __launch_bounds__(256) void kscan4(const float4* __restrict__ fq0,
                                              const float4* __restrict__ fq1,
                                              const float4* __restrict__ fq2,
                                              const int* __restrict__ len,
                                              const u32* __restrict__ list,
                                              u64* __restrict__ pd64,
                                              int cbase)
{
#pragma clang fp contract(off)
    __shared__ float4 c0s[CH_], c1s[CH_], c2s[CH_];
    const int t = blockIdx.x;
    const int base = (cbase + (int)blockIdx.y) * CH_;
    const int len_t = len[t];
    if (base >= len_t) return;                       // uniform exit
    const int tid = threadIdx.x;
    const int ii = (t >> 3) * 16 + (tid >> 4);
    const int jj = (t & 7) * 16 + (tid & 15);
    const int p  = ii * R_ + jj;
    const float px = pix_coord(jj);
    const float py = -pix_coord(ii);
    const u32* lp = list + (size_t)t * NF_ + base;
    const int K = min(CH_, len_t - base);

    // monotone 4B read of current depth word: stale => larger => safe bound
    u32 seed = ((const volatile u32*)pd64)[2 * p + 1];
    float bestd = __uint_as_float(seed);
    u64 best = ((u64)seed << 32) | 0xFFFFFFFFull;

    // chunk-level prune: list ascending by bucket; BKT_LO lower-bounds every
    // zmin_eff in this chunk. blo > bestd (all px) => no candidate can win or tie.
    float blo = BKT_LO(lp[0] >> 16);
    if (__syncthreads_and(blo > bestd)) return;

    if (tid < K) {
        int f = (int)(lp[tid] & 0xFFFFu);
        c0s[tid] = fq0[f];
        c1s[tid] = fq1[f];
        c2s[tid] = fq2[f];
    }
    __syncthreads();

    for (int k = 0; k < K; ++k) {
        float4 q1 = c1s[k];                   // x2,y2,det,zmin_eff
        if (q1.w > bestd) continue;           // strict: preserves exact ties
        float4 q0 = c0s[k];                   // a,b,c,d
        float dx = px - q1.x, dy = py - q1.y;
        float n0 = q0.x * dx + q0.y * dy;
        float n1 = q0.z * dx + q0.w * dy;
        u32 sd = __float_as_uint(q1.z) >> 31;
        bool s0 = (n0 == 0.0f) || ((__float_as_uint(n0) >> 31) == sd);
        bool s1 = (n1 == 0.0f) || ((__float_as_uint(n1) >> 31) == sd);
        if (!(s0 && s1)) continue;
        float w0 = n0 / q1.z;
        float w1 = n1 / q1.z;
        float w2 = 1.0f - w0 - w1;
        if (!(w2 >= 0.0f)) continue;
        float4 q2 = c2s[k];                   // z0,z1,z2,fid
        float invz = w0 / q2.x + w1 / q2.y + w2 / q2.z;
        if (invz > INV_FAR_F) {
            float clz = fminf(fmaxf(invz, INV_FAR_F), INV_NEAR_F);
            float dep = 1.0f / clz;
            u64 cand = ((u64)__float_as_uint(dep) << 32) | (u64)__float_as_uint(q2.w);
            if (cand < best) { best = cand; bestd = __uint_as_float((u32)(best >> 32)); }
        }
    }
    if ((u32)best != 0xFFFFFFFFu) atomicMin(&pd64[p], best);
}

// ---------------- fallback slice scan (ws too small; normally unused) ----------------
__global__ __launch_bounds__(256) void kscanS(const float4* __restrict__ fq0,
                                              const float4* __restrict__ fq1,
                                              const float4* __restrict__ fq2,
                                              const float4* __restrict__ bbx,
                                              const int* __restrict__ cull,
                                              u64* __restrict__ pd64)
{
#pragma clang fp contract(off)
    const int t = blockIdx.x, s = blockIdx.y;
    const int tid = threadIdx.x;
    const int ii = (t >> 3) * 16 + (tid >> 4);
    const int jj = (t & 7) * 16 + (tid & 15);
    const int p  = ii * R_ + jj;
    const float px = pix_coord(jj);
    const float py = -pix_coord(ii);
    const float tpx0 = pix_coord((t & 7) * 16), tpx1 = pix_coord((t & 7) * 16 + 15);
    const float tpy1 = -pix_coord((t >> 3) * 16), tpy0 = -pix_coord((t >> 3) * 16 + 15);
    const int f0 = s * FPS_, f1 = min(NF_, f0 + FPS_);

    u64 best = SENTINEL_ | 0xFFFFFFFFull;
    float bestd = 25.0f;

    for (int f = f0; f < f1; ++f) {
        if (cull[f]) continue;
        float4 bb = bbx[f];
        if (!(bb.x <= tpx1 && bb.y >= tpx0 && bb.z <= tpy1 && bb.w >= tpy0)) continue;
        float4 q1 = fq1[f];
        if (q1.w > bestd) continue;
        float4 q0 = fq0[f];
        float dx = px - q1.x, dy = py - q1.y;
        float n0 = q0.x * dx + q0.y * dy;
        float n1 = q0.z * dx + q0.w * dy;
        u32 sd = __float_as_uint(q1.z) >> 31;
        bool s0 = (n0 == 0.0f) || ((__float_as_uint(n0) >> 31) == sd);
        bool s1 = (n1 == 0.0f) || ((__float_as_uint(n1) >> 31) == sd);
        if (!(s0 && s1)) continue;
        float w0 = n0 / q1.z;
        float w1 = n1 / q1.z;
        float w2 = 1.0f - w0 - w1;
        if (!(w2 >= 0.0f)) continue;
        float4 q2 = fq2[f];
        float invz = w0 / q2.x + w1 / q2.y + w2 / q2.z;
        if (invz > INV_FAR_F) {
            float clz = fminf(fmaxf(invz, INV_FAR_F), INV_NEAR_F);
            float dep = 1.0f / clz;
            u64 cand = ((u64)__float_as_uint(dep) << 32) | (u64)__float_as_uint(q2.w);
            if (cand < best) { best = cand; bestd = __uint_as_float((u32)(best >> 32)); }
        }
    }
    if ((u32)best != 0xFFFFFFFFu) atomicMin(&pd64[p], best);
}

// ---------------- finalize ----------------
__global__ __launch_bounds__(256) void kfin(const u64* __restrict__ pd64,
                                            const float4* __restrict__ fq0,
                                            const float4* __restrict__ fq1,
                                            const float4* __restrict__ fq2,
                                            const float* __restrict__ tex,
                                            float* __restrict__ out)
{
#pragma clang fp contract(off)
    int p = blockIdx.x * 256 + threadIdx.x;
    if (p >= NPIX_) return;
    int ii = p >> 7, jj = p & 127;

    u64 v = pd64[p];
    float dep = __uint_as_float((u32)(v >> 32));
    int f = (int)(u32)v;

    float r = 0.0f, g = 0.0f, bl = 0.0f, s = 0.0f;
    if (dep < HIT_THR_F) {
        s = 1.0f;
        float4 q0 = fq0[f], q1 = fq1[f], q2 = fq2[f];
        float px = pix_coord(jj);
        float py = -pix_coord(ii);
        float dx = px - q1.x, dy = py - q1.y;
        float w0 = (q0.x * dx + q0.y * dy) / q1.z;
        float w1 = (q0.z * dx + q0.w * dy) / q1.z;
        float w2 = 1.0f - w0 - w1;
        float wt0 = (w0 / q2.x) * dep;
        float wt1 = (w1 / q2.y) * dep;
        float wt2 = (w2 / q2.z) * dep;
        int t0 = (int)fminf(fmaxf(floorf(wt0 * 3.0f), 0.0f), 2.0f);
        int t1 = (int)fminf(fmaxf(floorf(wt1 * 3.0f), 0.0f), 2.0f);
        int t2 = (int)fminf(fmaxf(floorf(wt2 * 3.0f), 0.0f), 2.0f);
        int lin = f * 27 + t0 * 9 + t1 * 3 + t2;
        r  = tex[lin * 3 + 0];
        g  = tex[lin * 3 + 1];
        bl = tex[lin * 3 + 2];
    }
    out[0 * NPIX_ + p] = r;
    out[1 * NPIX_ + p] = g;
    out[2 * NPIX_ + p] = bl;
    out[3 * NPIX_ + p] = s;
}

extern "C" void kernel_launch(void* const* d_in, const int* in_sizes, int n_in,
                              void* d_out, int out_size, void* d_ws, size_t ws_size,
                              hipStream_t stream) {
    const float* verts = (const float*)d_in[0];
    const float* tex   = (const float*)d_in[1];
    const int*   faces = (const int*)d_in[2];
    float* out = (float*)d_out;

    char* ws = (char*)d_ws;
    size_t off = 0;
    u64*    pd64 = (u64*)   (ws + off); off += (size_t)NPIX_ * 8;
    float4* fq0  = (float4*)(ws + off); off += (size_t)NF_ * 16;
    float4* fq1  = (float4*)(ws + off); off += (size_t)NF_ * 16;
    float4* fq2  = (float4*)(ws + off); off += (size_t)NF_ * 16;
    float4* bbx  = (float4*)(ws + off); off += (size_t)NF_ * 16;
    int*    cull = (int*)   (ws + off); off += (size_t)NF_ * 4;
    int*    lenp = (int*)   (ws + off); off += 64 * 4;
    u32*    cnt  = (u32*)   (ws + off); off += (size_t)64 * NBKT_ * 4;
    u32*    off2 = (u32*)   (ws + off); off += (size_t)64 * NBKT_ * 4;
    off = (off + 15) & ~(size_t)15;
    u32*    list = (u32*)   (ws + off);
    size_t need = off + (size_t)64 * NF_ * 4;
    int use_lists = (ws_size >= need) ? 1 : 0;

    const int FB = (NF_ + 255) / 256;
    kinit<<<NPIX_ / 256, 256, 0, stream>>>(pd64, cnt);
    kpre <<<FB, 256, 0, stream>>>(verts, faces, fq0, fq1, fq2, bbx, cull, cnt, use_lists);
    if (use_lists) {
        kprefix <<<64, 256, 0, stream>>>(cnt, off2, lenp);
        kscatter<<<FB, 256, 0, stream>>>(bbx, fq1, cull, off2, list);
        dim3 gA(64, A_CH_);
        kscan4<<<gA, 256, 0, stream>>>(fq0, fq1, fq2, lenp, list, pd64, 0);
        dim3 gB(64, B_CH_);
        kscan4<<<gB, 256, 0, stream>>>(fq0, fq1, fq2, lenp, list, pd64, A_CH_);
    } else {
        dim3 g(64, NSLICE_);
        kscanS<<<g, 256, 0, stream>>>(fq0, fq1, fq2, bbx, cull, pd64);
    }
    kfin<<<NPIX_ / 256, 256, 0, stream>>>(pd64, fq0, fq1, fq2, tex, out);
}

// Round 5
// 131.998 us; speedup vs baseline: 1.8924x; 1.5609x over previous
//
#include <hip/hip_runtime.h>
#include <math.h>
#include <stdint.h>

#define NF_     13776
#define R_      128
#define NPIX_   (R_ * R_)
#define CH_     256
#define NCHUNK_ ((NF_ + CH_ - 1) / CH_)          // 54
#define A_CH_   2
#define B_CH_   (NCHUNK_ - A_CH_)                // 52
#define NSLICE_ 32
#define FPS_    ((NF_ + NSLICE_ - 1) / NSLICE_)
#define NBKT_   256

typedef unsigned long long u64;
typedef unsigned int u32;

// exact f32 constants matching the JAX reference
#define EYEZ_F     (-2.7320508075688772935f)     // -(1/tan(30deg) + 1)
#define INV_FAR_F  (0.04f)
#define INV_NEAR_F (10.0f)
#define FAR_BITS   0x41C80000u                   // bits of 25.0f
#define HIT_THR_F  ((float)(25.0 * (1.0 - 1e-06)))
#define SENTINEL_  (((u64)FAR_BITS << 32))       // depth=FAR, fid=0
// z-bucket mapping: bucket = min(255, (int)(zeff*32)); BKT_LO(b) <= zmin_eff of all members
#define BKT_SCALE  32.0f
#define BKT_LO(b)  ((float)(b) * (0.03125f * 0.999999f))

static __device__ __forceinline__ float pix_coord(int j) {
    return (2.0f * (float)j + 1.0f - 128.0f) / 128.0f;   // exact in f32
}

static __device__ __forceinline__ void tile_masks(float4 bb, int& xm, int& ym) {
    xm = 0; ym = 0;
    #pragma unroll
    for (int t = 0; t < 8; ++t) {
        float tx0 = pix_coord(t * 16), tx1 = pix_coord(t * 16 + 15);
        if (bb.x <= tx1 && bb.y >= tx0) xm |= 1 << t;
        float ty1 = -pix_coord(t * 16), ty0 = -pix_coord(t * 16 + 15);
        if (bb.z <= ty1 && bb.w >= ty0) ym |= 1 << t;
    }
}

// ------- per-face preprocess + fused (tile,z-bucket) count + pd64 sentinel init -------
__global__ __launch_bounds__(256) void kpre(const float* __restrict__ verts,
                                            const int* __restrict__ faces,
                                            float4* __restrict__ fq0,
                                            float4* __restrict__ fq1,
                                            float4* __restrict__ fq2,
                                            float4* __restrict__ bbx,
                                            int* __restrict__ cull,
                                            u32* __restrict__ cnt,
                                            u64* __restrict__ pd64,
                                            int do_count)
{
#pragma clang fp contract(off)
    int idx = blockIdx.x * 256 + threadIdx.x;
    if (idx < NPIX_) pd64[idx] = SENTINEL_;          // depth buffer sentinel
    int f = idx;
    if (f >= NF_) return;
    int i0 = faces[3*f+0], i1 = faces[3*f+1], i2 = faces[3*f+2];
    float x0 = verts[3*i0+0], y0 = verts[3*i0+1], z0 = verts[3*i0+2] - EYEZ_F;
    float x1 = verts[3*i1+0], y1 = verts[3*i1+1], z1 = verts[3*i1+2] - EYEZ_F;
    float x2 = verts[3*i2+0], y2 = verts[3*i2+1], z2 = verts[3*i2+2] - EYEZ_F;

    float a = y1 - y2;
    float b = x2 - x1;
    float c = y2 - y0;
    float d = x0 - x2;
    float e = y0 - y2;
    float det = a * d + b * e;                   // no FMA (contract off)
    bool det_ok = fabsf(det) > 1e-10f;
    float dets = det_ok ? det : 1e-10f;
    bool zpos = (z0 > 0.1f) && (z1 > 0.1f) && (z2 > 0.1f);

    // conservative prune bound: any valid candidate's computed depth > zmin_eff (strict)
    float zmin_eff = fminf(z0, fminf(z1, z2)) * 0.99999f;

    float4 bb = make_float4(fminf(x0, fminf(x1, x2)) - 1e-4f,
                            fmaxf(x0, fmaxf(x1, x2)) + 1e-4f,
                            fminf(y0, fminf(y1, y2)) - 1e-4f,
                            fmaxf(y0, fmaxf(y1, y2)) + 1e-4f);
    int ok = (det_ok && zpos) ? 0 : 1;

    fq0[f] = make_float4(a, b, c, d);
    fq1[f] = make_float4(x2, y2, dets, zmin_eff);
    fq2[f] = make_float4(z0, z1, z2, __uint_as_float((u32)f));
    bbx[f] = bb;
    cull[f] = ok;

    if (do_count && ok == 0) {
        int xm, ym; tile_masks(bb, xm, ym);
        int bkt = min(255, (int)(zmin_eff * BKT_SCALE));
        for (int tr = 0; tr < 8; ++tr) if (ym & (1 << tr))
            for (int tc = 0; tc < 8; ++tc) if (xm & (1 << tc))
                atomicAdd(&cnt[(tr * 8 + tc) * NBKT_ + bkt], 1u);
    }
}

// ---------------- per-tile exclusive prefix over buckets ----------------
__global__ __launch_bounds__(256) void kprefix(const u32* __restrict__ count,
                                               u32* __restrict__ offs2,
                                               int* __restrict__ len)
{
    __shared__ u32 s[NBKT_];
    int t = blockIdx.x, b = threadIdx.x;
    u32 v = count[t * NBKT_ + b];
    s[b] = v;
    __syncthreads();
    for (int d = 1; d < NBKT_; d <<= 1) {
        u32 add = (b >= d) ? s[b - d] : 0;
        __syncthreads();
        s[b] += add;
        __syncthreads();
    }
    offs2[t * NBKT_ + b] = s[b] - v;     // exclusive
    if (b == NBKT_ - 1) len[t] = (int)s[NBKT_ - 1];
}

// ---------------- scatter faces into bucket-sorted per-tile lists ----------------
__global__ __launch_bounds__(256) void kscatter(const float4* __restrict__ bbx,
                                                const float4* __restrict__ fq1,
                                                const int* __restrict__ cull,
                                                u32* __restrict__ offs2,
                                                u32* __restrict__ list)
{
#pragma clang fp contract(off)
    int f = blockIdx.x * 256 + threadIdx.x;
    if (f >= NF_ || cull[f]) return;
    int xm, ym; tile_masks(bbx[f], xm, ym);
    int bkt = min(255, (int)(fq1[f].w * BKT_SCALE));
    u32 entry = ((u32)bkt << 16) | (u32)f;
    for (int tr = 0; tr < 8; ++tr) if (ym & (1 << tr))
        for (int tc = 0; tc < 8; ++tc) if (xm & (1 << tc)) {
            int t = tr * 8 + tc;
            u32 slot = atomicAdd(&offs2[t * NBKT_ + bkt], 1u);
            list[(size_t)t * NF_ + slot] = entry;
        }
}

// ------- scan: block = (tile, quadrant, chunk); 64 pixels x 4 candidate-groups -------
__global__ __launch_bounds__(256) void kscan5(const float4* __restrict__ fq0,
                                              const float4* __restrict__ fq1,
                                              const float4* __restrict__ fq2,
                                              const int* __restrict__ len,
                                              const u32* __restrict__ list,
                                              u64* __restrict__ pd64,
                                              int cbase)
{
#pragma clang fp contract(off)
    __shared__ float4 c0s[CH_], c1s[CH_], c2s[CH_];
    __shared__ u64 pb[256];
    const int bx = blockIdx.x;
    const int t = bx >> 2, q = bx & 3;               // tile, 8x8-px quadrant
    const int base = (cbase + (int)blockIdx.y) * CH_;
    const int len_t = len[t];
    if (base >= len_t) return;                       // uniform exit
    const int tid = threadIdx.x;
    const int g = tid >> 6, l = tid & 63;            // candidate-group (wave), pixel
    const int ii = (t >> 3) * 16 + (q >> 1) * 8 + (l >> 3);
    const int jj = (t & 7) * 16 + (q & 1) * 8 + (l & 7);
    const int p  = ii * R_ + jj;
    const float px = pix_coord(jj);
    const float py = -pix_coord(ii);
    const u32* lp = list + (size_t)t * NF_ + base;
    const int K = min(CH_, len_t - base);

    // monotone 4B read of current depth word: stale => larger => safe bound
    u32 seed = ((const volatile u32*)pd64)[2 * p + 1];
    float bestd = __uint_as_float(seed);
    u64 best = ((u64)seed << 32) | 0xFFFFFFFFull;

    // chunk prune: list ascending by bucket; BKT_LO lower-bounds every zmin_eff here.
    // blo > bestd for ALL pixels => no candidate in/after this chunk can win or tie.
    float blo = BKT_LO(lp[0] >> 16);
    if (__syncthreads_and(blo > bestd)) return;

    if (tid < K) {
        int f = (int)(lp[tid] & 0xFFFFu);
        c0s[tid] = fq0[f];
        c1s[tid] = fq1[f];
        c2s[tid] = fq2[f];
    }
    __syncthreads();

    // interleaved split: group g takes k = g, g+4, ... (all groups sweep ascending z)
    for (int k = g; k < K; k += 4) {
        float4 q1 = c1s[k];                   // x2,y2,det,zmin_eff (LDS broadcast)
        if (q1.w > bestd) continue;           // strict: preserves exact ties
        float4 q0 = c0s[k];                   // a,b,c,d
        float dx = px - q1.x, dy = py - q1.y;
        float n0 = q0.x * dx + q0.y * dy;
        float n1 = q0.z * dx + q0.w * dy;
        u32 sd = __float_as_uint(q1.z) >> 31;
        bool s0 = (n0 == 0.0f) || ((__float_as_uint(n0) >> 31) == sd);
        bool s1 = (n1 == 0.0f) || ((__float_as_uint(n1) >> 31) == sd);
        if (!(s0 && s1)) continue;
        float w0 = n0 / q1.z;
        float w1 = n1 / q1.z;
        float w2 = 1.0f - w0 - w1;
        if (!(w2 >= 0.0f)) continue;
        float4 q2 = c2s[k];                   // z0,z1,z2,fid
        float invz = w0 / q2.x + w1 / q2.y + w2 / q2.z;
        if (invz > INV_FAR_F) {
            float clz = fminf(fmaxf(invz, INV_FAR_F), INV_NEAR_F);
            float dep = 1.0f / clz;
            u64 cand = ((u64)__float_as_uint(dep) << 32) | (u64)__float_as_uint(q2.w);
            if (cand < best) { best = cand; bestd = __uint_as_float((u32)(best >> 32)); }
        }
    }

    // exact merge of 4 partial (depth,fid) mins per pixel
    pb[l * 4 + g] = best;
    __syncthreads();
    if (tid < 64) {
        u64 m = pb[tid * 4 + 0];
        u64 v1 = pb[tid * 4 + 1]; if (v1 < m) m = v1;
        u64 v2 = pb[tid * 4 + 2]; if (v2 < m) m = v2;
        u64 v3 = pb[tid * 4 + 3]; if (v3 < m) m = v3;
        if ((u32)m != 0xFFFFFFFFu) atomicMin(&pd64[p], m);
    }
}

// ---------------- fallback slice scan (ws too small; normally unused) ----------------
__global__ __launch_bounds__(256) void kscanS(const float4* __restrict__ fq0,
                                              const float4* __restrict__ fq1,
                                              const float4* __restrict__ fq2,
                                              const float4* __restrict__ bbx,
                                              const int* __restrict__ cull,
                                              u64* __restrict__ pd64)
{
#pragma clang fp contract(off)
    const int t = blockIdx.x, s = blockIdx.y;
    const int tid = threadIdx.x;
    const int ii = (t >> 3) * 16 + (tid >> 4);
    const int jj = (t & 7) * 16 + (tid & 15);
    const int p  = ii * R_ + jj;
    const float px = pix_coord(jj);
    const float py = -pix_coord(ii);
    const float tpx0 = pix_coord((t & 7) * 16), tpx1 = pix_coord((t & 7) * 16 + 15);
    const float tpy1 = -pix_coord((t >> 3) * 16), tpy0 = -pix_coord((t >> 3) * 16 + 15);
    const int f0 = s * FPS_, f1 = min(NF_, f0 + FPS_);

    u64 best = SENTINEL_ | 0xFFFFFFFFull;
    float bestd = 25.0f;

    for (int f = f0; f < f1; ++f) {
        if (cull[f]) continue;
        float4 bb = bbx[f];
        if (!(bb.x <= tpx1 && bb.y >= tpx0 && bb.z <= tpy1 && bb.w >= tpy0)) continue;
        float4 q1 = fq1[f];
        if (q1.w > bestd) continue;
        float4 q0 = fq0[f];
        float dx = px - q1.x, dy = py - q1.y;
        float n0 = q0.x * dx + q0.y * dy;
        float n1 = q0.z * dx + q0.w * dy;
        u32 sd = __float_as_uint(q1.z) >> 31;
        bool s0 = (n0 == 0.0f) || ((__float_as_uint(n0) >> 31) == sd);
        bool s1 = (n1 == 0.0f) || ((__float_as_uint(n1) >> 31) == sd);
        if (!(s0 && s1)) continue;
        float w0 = n0 / q1.z;
        float w1 = n1 / q1.z;
        float w2 = 1.0f - w0 - w1;
        if (!(w2 >= 0.0f)) continue;
        float4 q2 = fq2[f];
        float invz = w0 / q2.x + w1 / q2.y + w2 / q2.z;
        if (invz > INV_FAR_F) {
            float clz = fminf(fmaxf(invz, INV_FAR_F), INV_NEAR_F);
            float dep = 1.0f / clz;
            u64 cand = ((u64)__float_as_uint(dep) << 32) | (u64)__float_as_uint(q2.w);
            if (cand < best) { best = cand; bestd = __uint_as_float((u32)(best >> 32)); }
        }
    }
    if ((u32)best != 0xFFFFFFFFu) atomicMin(&pd64[p], best);
}

// ---------------- finalize ----------------
__global__ __launch_bounds__(256) void kfin(const u64* __restrict__ pd64,
                                            const float4* __restrict__ fq0,
                                            const float4* __restrict__ fq1,
                                            const float4* __restrict__ fq2,
                                            const float* __restrict__ tex,
                                            float* __restrict__ out)
{
#pragma clang fp contract(off)
    int p = blockIdx.x * 256 + threadIdx.x;
    if (p >= NPIX_) return;
    int ii = p >> 7, jj = p & 127;

    u64 v = pd64[p];
    float dep = __uint_as_float((u32)(v >> 32));
    int f = (int)(u32)v;

    float r = 0.0f, g = 0.0f, bl = 0.0f, s = 0.0f;
    if (dep < HIT_THR_F) {
        s = 1.0f;
        float4 q0 = fq0[f], q1 = fq1[f], q2 = fq2[f];
        float px = pix_coord(jj);
        float py = -pix_coord(ii);
        float dx = px - q1.x, dy = py - q1.y;
        float w0 = (q0.x * dx + q0.y * dy) / q1.z;
        float w1 = (q0.z * dx + q0.w * dy) / q1.z;
        float w2 = 1.0f - w0 - w1;
        float wt0 = (w0 / q2.x) * dep;
        float wt1 = (w1 / q2.y) * dep;
        float wt2 = (w2 / q2.z) * dep;
        int t0 = (int)fminf(fmaxf(floorf(wt0 * 3.0f), 0.0f), 2.0f);
        int t1 = (int)fminf(fmaxf(floorf(wt1 * 3.0f), 0.0f), 2.0f);
        int t2 = (int)fminf(fmaxf(floorf(wt2 * 3.0f), 0.0f), 2.0f);
        int lin = f * 27 + t0 * 9 + t1 * 3 + t2;
        r  = tex[lin * 3 + 0];
        g  = tex[lin * 3 + 1];
        bl = tex[lin * 3 + 2];
    }
    out[0 * NPIX_ + p] = r;
    out[1 * NPIX_ + p] = g;
    out[2 * NPIX_ + p] = bl;
    out[3 * NPIX_ + p] = s;
}

extern "C" void kernel_launch(void* const* d_in, const int* in_sizes, int n_in,
                              void* d_out, int out_size, void* d_ws, size_t ws_size,
                              hipStream_t stream) {
    const float* verts = (const float*)d_in[0];
    const float* tex   = (const float*)d_in[1];
    const int*   faces = (const int*)d_in[2];
    float* out = (float*)d_out;

    char* ws = (char*)d_ws;
    size_t off = 0;
    u64*    pd64 = (u64*)   (ws + off); off += (size_t)NPIX_ * 8;
    float4* fq0  = (float4*)(ws + off); off += (size_t)NF_ * 16;
    float4* fq1  = (float4*)(ws + off); off += (size_t)NF_ * 16;
    float4* fq2  = (float4*)(ws + off); off += (size_t)NF_ * 16;
    float4* bbx  = (float4*)(ws + off); off += (size_t)NF_ * 16;
    int*    cull = (int*)   (ws + off); off += (size_t)NF_ * 4;
    int*    lenp = (int*)   (ws + off); off += 64 * 4;
    u32*    cnt  = (u32*)   (ws + off); off += (size_t)64 * NBKT_ * 4;
    u32*    off2 = (u32*)   (ws + off); off += (size_t)64 * NBKT_ * 4;
    off = (off + 15) & ~(size_t)15;
    u32*    list = (u32*)   (ws + off);
    size_t need = off + (size_t)64 * NF_ * 4;
    int use_lists = (ws_size >= need) ? 1 : 0;

    const int FB = (NF_ + 255) / 256;       // 54
    hipMemsetAsync(cnt, 0, (size_t)64 * NBKT_ * 4, stream);
    kpre<<<NPIX_ / 256, 256, 0, stream>>>(verts, faces, fq0, fq1, fq2, bbx, cull,
                                          cnt, pd64, use_lists);
    if (use_lists) {
        kprefix <<<64, 256, 0, stream>>>(cnt, off2, lenp);
        kscatter<<<FB, 256, 0, stream>>>(bbx, fq1, cull, off2, list);
        dim3 gA(256, A_CH_);
        kscan5<<<gA, 256, 0, stream>>>(fq0, fq1, fq2, lenp, list, pd64, 0);
        dim3 gB(256, B_CH_);
        kscan5<<<gB, 256, 0, stream>>>(fq0, fq1, fq2, lenp, list, pd64, A_CH_);
    } else {
        dim3 g(64, NSLICE_);
        kscanS<<<g, 256, 0, stream>>>(fq0, fq1, fq2, bbx, cull, pd64);
    }
    kfin<<<NPIX_ / 256, 256, 0, stream>>>(pd64, fq0, fq1, fq2, tex, out);
}

// Round 6
// 80.972 us; speedup vs baseline: 3.0849x; 1.6302x over previous
//
#include <hip/hip_runtime.h>
#include <math.h>
#include <stdint.h>

#define NF_     13776
#define R_      128
#define NPIX_   (R_ * R_)
#define CH_     256
#define NCHUNK_ ((NF_ + CH_ - 1) / CH_)          // 54
#define A_CH_   2
#define B_CH_   (NCHUNK_ - A_CH_)                // 52
#define NSLICE_ 32
#define FPS_    ((NF_ + NSLICE_ - 1) / NSLICE_)
#define NBKT_   256

typedef unsigned long long u64;
typedef unsigned int u32;

// exact f32 constants matching the JAX reference
#define EYEZ_F     (-2.7320508075688772935f)     // -(1/tan(30deg) + 1)
#define INV_FAR_F  (0.04f)
#define INV_NEAR_F (10.0f)
#define FAR_BITS   0x41C80000u                   // bits of 25.0f
#define HIT_THR_F  ((float)(25.0 * (1.0 - 1e-06)))
#define SENTINEL_  (((u64)FAR_BITS << 32))       // depth=FAR, fid=0
// z-bucket mapping: bucket = min(255, (int)(zeff*32)); BKT_LO(b) <= zmin_eff of all members
#define BKT_SCALE  32.0f
#define BKT_LO(b)  ((float)(b) * (0.03125f * 0.999999f))

static __device__ __forceinline__ float pix_coord(int j) {
    return (2.0f * (float)j + 1.0f - 128.0f) / 128.0f;   // exact in f32
}

static __device__ __forceinline__ void tile_masks(float4 bb, int& xm, int& ym) {
    xm = 0; ym = 0;
    #pragma unroll
    for (int t = 0; t < 8; ++t) {
        float tx0 = pix_coord(t * 16), tx1 = pix_coord(t * 16 + 15);
        if (bb.x <= tx1 && bb.y >= tx0) xm |= 1 << t;
        float ty1 = -pix_coord(t * 16), ty0 = -pix_coord(t * 16 + 15);
        if (bb.z <= ty1 && bb.w >= ty0) ym |= 1 << t;
    }
}

// ------- per-face preprocess + packed face-word + pd64 sentinel init -------
__global__ __launch_bounds__(256) void kpre(const float* __restrict__ verts,
                                            const int* __restrict__ faces,
                                            float4* __restrict__ fq0,
                                            float4* __restrict__ fq1,
                                            float4* __restrict__ fq2,
                                            float4* __restrict__ bbx,
                                            int* __restrict__ cull,
                                            u32* __restrict__ fw,
                                            u64* __restrict__ pd64)
{
#pragma clang fp contract(off)
    int idx = blockIdx.x * 256 + threadIdx.x;
    if (idx < NPIX_) pd64[idx] = SENTINEL_;          // depth buffer sentinel
    int f = idx;
    if (f >= NF_) return;
    int i0 = faces[3*f+0], i1 = faces[3*f+1], i2 = faces[3*f+2];
    float x0 = verts[3*i0+0], y0 = verts[3*i0+1], z0 = verts[3*i0+2] - EYEZ_F;
    float x1 = verts[3*i1+0], y1 = verts[3*i1+1], z1 = verts[3*i1+2] - EYEZ_F;
    float x2 = verts[3*i2+0], y2 = verts[3*i2+1], z2 = verts[3*i2+2] - EYEZ_F;

    float a = y1 - y2;
    float b = x2 - x1;
    float c = y2 - y0;
    float d = x0 - x2;
    float e = y0 - y2;
    float det = a * d + b * e;                   // no FMA (contract off)
    bool det_ok = fabsf(det) > 1e-10f;
    float dets = det_ok ? det : 1e-10f;
    bool zpos = (z0 > 0.1f) && (z1 > 0.1f) && (z2 > 0.1f);

    // conservative prune bound: any valid candidate's computed depth > zmin_eff (strict)
    float zmin_eff = fminf(z0, fminf(z1, z2)) * 0.99999f;

    float4 bb = make_float4(fminf(x0, fminf(x1, x2)) - 1e-4f,
                            fmaxf(x0, fmaxf(x1, x2)) + 1e-4f,
                            fminf(y0, fminf(y1, y2)) - 1e-4f,
                            fmaxf(y0, fmaxf(y1, y2)) + 1e-4f);
    int ok = (det_ok && zpos) ? 0 : 1;

    fq0[f] = make_float4(a, b, c, d);
    fq1[f] = make_float4(x2, y2, dets, zmin_eff);
    fq2[f] = make_float4(z0, z1, z2, __uint_as_float((u32)f));
    bbx[f] = bb;
    cull[f] = ok;

    u32 w = 0;
    if (ok == 0) {
        int xm, ym; tile_masks(bb, xm, ym);
        u32 bkt = (u32)min(255, (int)(zmin_eff * BKT_SCALE));
        w = (u32)xm | ((u32)ym << 8) | (bkt << 16);
    }
    fw[f] = w;
}

// ------- per-tile count + prefix + scatter, all in LDS (1 block = 1 tile) -------
__global__ __launch_bounds__(256) void kbinsort(const u32* __restrict__ fw,
                                                u32* __restrict__ list,
                                                int* __restrict__ len)
{
    __shared__ u32 lcnt[NBKT_];
    __shared__ u32 loff[NBKT_];
    const int t = blockIdx.x;
    const int tr = t >> 3, tc = t & 7;
    const int tid = threadIdx.x;
    lcnt[tid] = 0;
    __syncthreads();

    // pass 1: count into LDS buckets (non-returning LDS atomics)
    for (int f = tid; f < NF_; f += 256) {
        u32 w = fw[f];
        if (((w >> tc) & 1u) && ((w >> (8 + tr)) & 1u))
            atomicAdd(&lcnt[(w >> 16) & 0xFFu], 1u);
    }
    __syncthreads();

    // exclusive prefix over 256 buckets (Hillis-Steele in LDS)
    u32 v = lcnt[tid];
    loff[tid] = v;
    __syncthreads();
    for (int d = 1; d < NBKT_; d <<= 1) {
        u32 add = (tid >= d) ? loff[tid - d] : 0;
        __syncthreads();
        loff[tid] += add;
        __syncthreads();
    }
    u32 incl = loff[tid];
    __syncthreads();
    loff[tid] = incl - v;                        // exclusive
    if (tid == NBKT_ - 1) len[t] = (int)incl;
    __syncthreads();

    // pass 2: scatter with returning LDS atomics (cheap)
    for (int f = tid; f < NF_; f += 256) {
        u32 w = fw[f];
        if (((w >> tc) & 1u) && ((w >> (8 + tr)) & 1u)) {
            u32 bkt = (w >> 16) & 0xFFu;
            u32 slot = atomicAdd(&loff[bkt], 1u);
            list[(size_t)t * NF_ + slot] = (bkt << 16) | (u32)f;
        }
    }
}

// ------- scan: block = (tile, quadrant, chunk); 64 pixels x 4 candidate-groups -------
__global__ __launch_bounds__(256) void kscan5(const float4* __restrict__ fq0,
                                              const float4* __restrict__ fq1,
                                              const float4* __restrict__ fq2,
                                              const int* __restrict__ len,
                                              const u32* __restrict__ list,
                                              u64* __restrict__ pd64,
                                              int cbase)
{
#pragma clang fp contract(off)
    __shared__ float4 c0s[CH_], c1s[CH_], c2s[CH_];
    __shared__ u64 pb[256];
    const int bx = blockIdx.x;
    const int t = bx >> 2, q = bx & 3;               // tile, 8x8-px quadrant
    const int base = (cbase + (int)blockIdx.y) * CH_;
    const int len_t = len[t];
    if (base >= len_t) return;                       // uniform exit
    const int tid = threadIdx.x;
    const int g = tid >> 6, l = tid & 63;            // candidate-group (wave), pixel
    const int ii = (t >> 3) * 16 + (q >> 1) * 8 + (l >> 3);
    const int jj = (t & 7) * 16 + (q & 1) * 8 + (l & 7);
    const int p  = ii * R_ + jj;
    const float px = pix_coord(jj);
    const float py = -pix_coord(ii);
    const u32* lp = list + (size_t)t * NF_ + base;
    const int K = min(CH_, len_t - base);

    // monotone 4B read of current depth word: stale => larger => safe bound
    u32 seed = ((const volatile u32*)pd64)[2 * p + 1];
    float bestd = __uint_as_float(seed);
    u64 best = ((u64)seed << 32) | 0xFFFFFFFFull;

    // chunk prune: list ascending by bucket; BKT_LO lower-bounds every zmin_eff here.
    // blo > bestd for ALL pixels => no candidate in/after this chunk can win or tie.
    float blo = BKT_LO(lp[0] >> 16);
    if (__syncthreads_and(blo > bestd)) return;

    if (tid < K) {
        int f = (int)(lp[tid] & 0xFFFFu);
        c0s[tid] = fq0[f];
        c1s[tid] = fq1[f];
        c2s[tid] = fq2[f];
    }
    __syncthreads();

    // interleaved split: group g takes k = g, g+4, ... (all groups sweep ascending z)
    for (int k = g; k < K; k += 4) {
        float4 q1 = c1s[k];                   // x2,y2,det,zmin_eff (LDS broadcast)
        if (q1.w > bestd) continue;           // strict: preserves exact ties
        float4 q0 = c0s[k];                   // a,b,c,d
        float dx = px - q1.x, dy = py - q1.y;
        float n0 = q0.x * dx + q0.y * dy;
        float n1 = q0.z * dx + q0.w * dy;
        u32 sd = __float_as_uint(q1.z) >> 31;
        bool s0 = (n0 == 0.0f) || ((__float_as_uint(n0) >> 31) == sd);
        bool s1 = (n1 == 0.0f) || ((__float_as_uint(n1) >> 31) == sd);
        if (!(s0 && s1)) continue;
        float w0 = n0 / q1.z;
        float w1 = n1 / q1.z;
        float w2 = 1.0f - w0 - w1;
        if (!(w2 >= 0.0f)) continue;
        float4 q2 = c2s[k];                   // z0,z1,z2,fid
        float invz = w0 / q2.x + w1 / q2.y + w2 / q2.z;
        if (invz > INV_FAR_F) {
            float clz = fminf(fmaxf(invz, INV_FAR_F), INV_NEAR_F);
            float dep = 1.0f / clz;
            u64 cand = ((u64)__float_as_uint(dep) << 32) | (u64)__float_as_uint(q2.w);
            if (cand < best) { best = cand; bestd = __uint_as_float((u32)(best >> 32)); }
        }
    }

    // exact merge of 4 partial (depth,fid) mins per pixel
    pb[l * 4 + g] = best;
    __syncthreads();
    if (tid < 64) {
        u64 m = pb[tid * 4 + 0];
        u64 v1 = pb[tid * 4 + 1]; if (v1 < m) m = v1;
        u64 v2 = pb[tid * 4 + 2]; if (v2 < m) m = v2;
        u64 v3 = pb[tid * 4 + 3]; if (v3 < m) m = v3;
        if ((u32)m != 0xFFFFFFFFu) atomicMin(&pd64[p], m);
    }
}

// ---------------- fallback slice scan (ws too small; normally unused) ----------------
__global__ __launch_bounds__(256) void kscanS(const float4* __restrict__ fq0,
                                              const float4* __restrict__ fq1,
                                              const float4* __restrict__ fq2,
                                              const float4* __restrict__ bbx,
                                              const int* __restrict__ cull,
                                              u64* __restrict__ pd64)
{
#pragma clang fp contract(off)
    const int t = blockIdx.x, s = blockIdx.y;
    const int tid = threadIdx.x;
    const int ii = (t >> 3) * 16 + (tid >> 4);
    const int jj = (t & 7) * 16 + (tid & 15);
    const int p  = ii * R_ + jj;
    const float px = pix_coord(jj);
    const float py = -pix_coord(ii);
    const float tpx0 = pix_coord((t & 7) * 16), tpx1 = pix_coord((t & 7) * 16 + 15);
    const float tpy1 = -pix_coord((t >> 3) * 16), tpy0 = -pix_coord((t >> 3) * 16 + 15);
    const int f0 = s * FPS_, f1 = min(NF_, f0 + FPS_);

    u64 best = SENTINEL_ | 0xFFFFFFFFull;
    float bestd = 25.0f;

    for (int f = f0; f < f1; ++f) {
        if (cull[f]) continue;
        float4 bb = bbx[f];
        if (!(bb.x <= tpx1 && bb.y >= tpx0 && bb.z <= tpy1 && bb.w >= tpy0)) continue;
        float4 q1 = fq1[f];
        if (q1.w > bestd) continue;
        float4 q0 = fq0[f];
        float dx = px - q1.x, dy = py - q1.y;
        float n0 = q0.x * dx + q0.y * dy;
        float n1 = q0.z * dx + q0.w * dy;
        u32 sd = __float_as_uint(q1.z) >> 31;
        bool s0 = (n0 == 0.0f) || ((__float_as_uint(n0) >> 31) == sd);
        bool s1 = (n1 == 0.0f) || ((__float_as_uint(n1) >> 31) == sd);
        if (!(s0 && s1)) continue;
        float w0 = n0 / q1.z;
        float w1 = n1 / q1.z;
        float w2 = 1.0f - w0 - w1;
        if (!(w2 >= 0.0f)) continue;
        float4 q2 = fq2[f];
        float invz = w0 / q2.x + w1 / q2.y + w2 / q2.z;
        if (invz > INV_FAR_F) {
            float clz = fminf(fmaxf(invz, INV_FAR_F), INV_NEAR_F);
            float dep = 1.0f / clz;
            u64 cand = ((u64)__float_as_uint(dep) << 32) | (u64)__float_as_uint(q2.w);
            if (cand < best) { best = cand; bestd = __uint_as_float((u32)(best >> 32)); }
        }
    }
    if ((u32)best != 0xFFFFFFFFu) atomicMin(&pd64[p], best);
}

// ---------------- finalize ----------------
__global__ __launch_bounds__(256) void kfin(const u64* __restrict__ pd64,
                                            const float4* __restrict__ fq0,
                                            const float4* __restrict__ fq1,
                                            const float4* __restrict__ fq2,
                                            const float* __restrict__ tex,
                                            float* __restrict__ out)
{
#pragma clang fp contract(off)
    int p = blockIdx.x * 256 + threadIdx.x;
    if (p >= NPIX_) return;
    int ii = p >> 7, jj = p & 127;

    u64 v = pd64[p];
    float dep = __uint_as_float((u32)(v >> 32));
    int f = (int)(u32)v;

    float r = 0.0f, g = 0.0f, bl = 0.0f, s = 0.0f;
    if (dep < HIT_THR_F) {
        s = 1.0f;
        float4 q0 = fq0[f], q1 = fq1[f], q2 = fq2[f];
        float px = pix_coord(jj);
        float py = -pix_coord(ii);
        float dx = px - q1.x, dy = py - q1.y;
        float w0 = (q0.x * dx + q0.y * dy) / q1.z;
        float w1 = (q0.z * dx + q0.w * dy) / q1.z;
        float w2 = 1.0f - w0 - w1;
        float wt0 = (w0 / q2.x) * dep;
        float wt1 = (w1 / q2.y) * dep;
        float wt2 = (w2 / q2.z) * dep;
        int t0 = (int)fminf(fmaxf(floorf(wt0 * 3.0f), 0.0f), 2.0f);
        int t1 = (int)fminf(fmaxf(floorf(wt1 * 3.0f), 0.0f), 2.0f);
        int t2 = (int)fminf(fmaxf(floorf(wt2 * 3.0f), 0.0f), 2.0f);
        int lin = f * 27 + t0 * 9 + t1 * 3 + t2;
        r  = tex[lin * 3 + 0];
        g  = tex[lin * 3 + 1];
        bl = tex[lin * 3 + 2];
    }
    out[0 * NPIX_ + p] = r;
    out[1 * NPIX_ + p] = g;
    out[2 * NPIX_ + p] = bl;
    out[3 * NPIX_ + p] = s;
}

extern "C" void kernel_launch(void* const* d_in, const int* in_sizes, int n_in,
                              void* d_out, int out_size, void* d_ws, size_t ws_size,
                              hipStream_t stream) {
    const float* verts = (const float*)d_in[0];
    const float* tex   = (const float*)d_in[1];
    const int*   faces = (const int*)d_in[2];
    float* out = (float*)d_out;

    char* ws = (char*)d_ws;
    size_t off = 0;
    u64*    pd64 = (u64*)   (ws + off); off += (size_t)NPIX_ * 8;
    float4* fq0  = (float4*)(ws + off); off += (size_t)NF_ * 16;
    float4* fq1  = (float4*)(ws + off); off += (size_t)NF_ * 16;
    float4* fq2  = (float4*)(ws + off); off += (size_t)NF_ * 16;
    float4* bbx  = (float4*)(ws + off); off += (size_t)NF_ * 16;
    int*    cull = (int*)   (ws + off); off += (size_t)NF_ * 4;
    u32*    fw   = (u32*)   (ws + off); off += (size_t)NF_ * 4;
    int*    lenp = (int*)   (ws + off); off += 64 * 4;
    off = (off + 15) & ~(size_t)15;
    u32*    list = (u32*)   (ws + off);
    size_t need = off + (size_t)64 * NF_ * 4;
    int use_lists = (ws_size >= need) ? 1 : 0;

    kpre<<<NPIX_ / 256, 256, 0, stream>>>(verts, faces, fq0, fq1, fq2, bbx, cull,
                                          fw, pd64);
    if (use_lists) {
        kbinsort<<<64, 256, 0, stream>>>(fw, list, lenp);
        dim3 gA(256, A_CH_);
        kscan5<<<gA, 256, 0, stream>>>(fq0, fq1, fq2, lenp, list, pd64, 0);
        dim3 gB(256, B_CH_);
        kscan5<<<gB, 256, 0, stream>>>(fq0, fq1, fq2, lenp, list, pd64, A_CH_);
    } else {
        dim3 g(64, NSLICE_);
        kscanS<<<g, 256, 0, stream>>>(fq0, fq1, fq2, bbx, cull, pd64);
    }
    kfin<<<NPIX_ / 256, 256, 0, stream>>>(pd64, fq0, fq1, fq2, tex, out);
}